// Round 1
// baseline (534.903 us; speedup 1.0000x reference)
//
#include <hip/hip_runtime.h>
#include <math.h>

#define TOKENS 16384
#define EMBD   4096
#define NEXP   64
#define TOPK   8
#define KSPLIT 8
#define KSLICE (EMBD / KSPLIT)   /* 512 */
#define CHUNK  16

// ---------------------------------------------------------------------------
// Kernel 1: transpose W[64][4096] -> Wt[4096][64] so that for a fixed k the 64
// expert weights are contiguous (enables s_load_dwordx16 scalar loads in GEMM).
// ---------------------------------------------------------------------------
__global__ void transpose_w(const float* __restrict__ W, float* __restrict__ Wt) {
    int idx = blockIdx.x * blockDim.x + threadIdx.x;  // idx = e*4096 + k, coalesced read
    int e = idx >> 12;
    int k = idx & 4095;
    Wt[k * NEXP + e] = W[idx];
}

// ---------------------------------------------------------------------------
// Kernel 2: partial GEMM. lane = token, each lane accumulates all 64 expert
// logits for its token over a K-slice of 512. W values are wave-uniform ->
// scalar loads; x values are per-lane row-streaming float4 loads.
// Accuracy: fp32 FMA within chunks of 16, f64 outer accumulation.
// Grid: (64 token-blocks of 256 tokens) x (8 K-slices) = 512 blocks.
// ---------------------------------------------------------------------------
__global__ __launch_bounds__(256, 2) void gemm_partial(
    const float* __restrict__ x, const float* __restrict__ Wt,
    float* __restrict__ part) {
    const int lane = threadIdx.x & 63;
    const int wave = threadIdx.x >> 6;
    const int tok  = blockIdx.x * 256 + wave * 64 + lane;
    const int ks   = blockIdx.y;
    const int kbase = ks * KSLICE;

    const float* xrow = x + (size_t)tok * EMBD + kbase;

    double accd[NEXP];
#pragma unroll
    for (int e = 0; e < NEXP; ++e) accd[e] = 0.0;

    for (int kc = 0; kc < KSLICE; kc += CHUNK) {
        const float4* xp = (const float4*)(xrow + kc);
        float4 a = xp[0], b = xp[1], c = xp[2], d4 = xp[3];
        float xv[CHUNK] = {a.x, a.y, a.z, a.w,  b.x, b.y, b.z, b.w,
                           c.x, c.y, c.z, c.w,  d4.x, d4.y, d4.z, d4.w};

        float accf[NEXP];
#pragma unroll
        for (int e = 0; e < NEXP; ++e) accf[e] = 0.0f;

#pragma unroll
        for (int j = 0; j < CHUNK; ++j) {
            const float xj = xv[j];
            const float* wrow = Wt + (size_t)(kbase + kc + j) * NEXP;  // wave-uniform
#pragma unroll
            for (int e = 0; e < NEXP; ++e)
                accf[e] = fmaf(wrow[e], xj, accf[e]);
        }

#pragma unroll
        for (int e = 0; e < NEXP; ++e) accd[e] += (double)accf[e];
    }

    float* dst = part + ((size_t)ks * TOKENS + tok) * NEXP;
#pragma unroll
    for (int e = 0; e < NEXP; ++e) dst[e] = (float)accd[e];
}

// ---------------------------------------------------------------------------
// Kernel 3: reduce K-split partials (fixed order, f64 -> deterministic),
// top-8 via 8 rounds of 64-lane argmax butterfly (tie-break: lower index,
// matching jax.lax.top_k), masked softmax, write probs + indices(as float).
// One wave per token.
// ---------------------------------------------------------------------------
__global__ __launch_bounds__(256) void topk_softmax(
    const float* __restrict__ part, float* __restrict__ probs,
    float* __restrict__ idxout) {
    const int lane = threadIdx.x & 63;   // = expert
    const int wave = threadIdx.x >> 6;
    const int tok  = blockIdx.x * 4 + wave;

    double d = 0.0;
#pragma unroll
    for (int s = 0; s < KSPLIT; ++s)
        d += (double)part[((size_t)s * TOKENS + tok) * NEXP + lane];
    const float logit = (float)d;

    float v = logit;
    float m = 0.0f, denom = 0.0f;
    int myidx = 0;
    unsigned long long selmask = 0ull;

    for (int r = 0; r < TOPK; ++r) {
        float bv = v;
        int   bi = lane;
#pragma unroll
        for (int off = 32; off > 0; off >>= 1) {
            float ov = __shfl_xor(bv, off);
            int   oi = __shfl_xor(bi, off);
            if (ov > bv || (ov == bv && oi < bi)) { bv = ov; bi = oi; }
        }
        if (r == 0) m = bv;              // rounds are descending -> round 0 is max
        denom += expf(bv - m);
        selmask |= 1ull << bi;
        if (lane == r) myidx = bi;       // lane r keeps the rank-r index
        if (lane == bi) v = -INFINITY;   // remove winner for next round
    }

    const float p = ((selmask >> lane) & 1ull) ? (expf(logit - m) / denom) : 0.0f;
    probs[(size_t)tok * NEXP + lane] = p;
    if (lane < TOPK) idxout[(size_t)tok * TOPK + lane] = (float)myidx;
}

// ---------------------------------------------------------------------------
extern "C" void kernel_launch(void* const* d_in, const int* in_sizes, int n_in,
                              void* d_out, int out_size, void* d_ws, size_t ws_size,
                              hipStream_t stream) {
    const float* x = (const float*)d_in[0];   // [4,4096,4096]
    const float* W = (const float*)d_in[1];   // [64,4096]

    float* out    = (float*)d_out;
    float* probs  = out;                        // 16384*64 floats
    float* idxout = out + (size_t)TOKENS * NEXP; // 16384*8 floats (indices as float)

    float* Wt   = (float*)d_ws;                       // 4096*64 floats = 1 MB
    float* part = Wt + (size_t)EMBD * NEXP;           // 8*16384*64 floats = 32 MB

    hipLaunchKernelGGL(transpose_w, dim3((EMBD * NEXP) / 256), dim3(256), 0, stream,
                       W, Wt);
    hipLaunchKernelGGL(gemm_partial, dim3(TOKENS / 256, KSPLIT), dim3(256), 0, stream,
                       x, Wt, part);
    hipLaunchKernelGGL(topk_softmax, dim3(TOKENS / 4), dim3(256), 0, stream,
                       part, probs, idxout);
}